// Round 2
// baseline (246.547 us; speedup 1.0000x reference)
//
#include <hip/hip_runtime.h>

typedef short short8 __attribute__((ext_vector_type(8)));
typedef float floatx4 __attribute__((ext_vector_type(4)));

#define INF 4096

// fp32 -> bf16 round-to-nearest-even
__device__ __forceinline__ ushort f2bf(float f) {
  unsigned u = __builtin_bit_cast(unsigned, f);
  u += 0x7fffu + ((u >> 16) & 1u);
  return (ushort)(u >> 16);
}

// W-stationary block-diagonal GEMM.
// Grid: 256 WGs = 16 k-blocks x 16 m-groups; 512 threads (8 waves); 1 WG/CU.
// W_k (256x256) lives in LDS as bf16 (128 KB, 16B-chunk XOR swizzle -> 2-way max
// bank aliasing on ds_read_b128, which is free). Each WG streams 16 m-tiles of
// 64 rows; x goes global->regs (half-tile ahead, register double buffer), bf16
// cvt at use, 16x16x32 MFMA, bias+store. NO barriers in the main loop: waves
// run free, keeping a continuous stream of outstanding loads (the round-1
// kernel drained vmcnt+barrier every 4 short iterations -> 2.7 TB/s).
__global__ __launch_bounds__(512, 2) void bd_gemm(
    const float* __restrict__ x, const float* __restrict__ W,
    const float* __restrict__ bias, float* __restrict__ out)
{
  __shared__ ushort wlds[256 * 256];  // [n][k] bf16, swizzled: chunk kc -> kc ^ (n&7)

  const int bid  = blockIdx.x;
  const int kb   = bid >> 4;   // k-block 0..15
  const int mg   = bid & 15;   // m-group (1024 rows each)
  const int tid  = threadIdx.x;
  const int lane = tid & 63;
  const int wid  = tid >> 6;   // 0..7
  const int wm   = wid >> 1;   // 16-row group within the 64-row tile
  const int wn   = wid & 1;    // 128-col half of the 256-col block
  const int ln   = lane & 15;
  const int lk   = lane >> 4;  // 0..3 (k-chunk within MFMA frag)

  // ---- x tile-0 half-0 loads issued FIRST (latency hides under W prologue) ----
  floatx4 sA[2][4][2];  // [buf][q][pair] : one 16rows x 128K fp32 half-tile per buf
  const float* xp = x + ((size_t)mg * 1024 + wm * 16 + ln) * INF + kb * 256 + lk * 8;

#define LOADH(buf, t, h)                                                    \
  _Pragma("unroll") for (int q = 0; q < 4; ++q) {                           \
    const float* s_ = xp + (size_t)(t) * 64 * INF + ((h) * 4 + q) * 32;     \
    sA[buf][q][0] = *(const floatx4*)s_;                                    \
    sA[buf][q][1] = *(const floatx4*)(s_ + 4);                              \
  }

  LOADH(0, 0, 0)

  // ---- prologue: W_k fp32 -> bf16 -> LDS (swizzled), coalesced ----
  {
    const float* wsrc = W + (size_t)kb * 65536;
#pragma unroll
    for (int p = 0; p < 16; ++p) {
      const int id = tid + p * 512;
      const int n  = id >> 5;   // out-col (B row)
      const int kc = id & 31;   // 8-elem chunk along k
      const float* s_ = wsrc + n * 256 + kc * 8;
      floatx4 v0 = *(const floatx4*)s_;
      floatx4 v1 = *(const floatx4*)(s_ + 4);
      short8 u;
#pragma unroll
      for (int j = 0; j < 4; ++j) {
        u[j]     = (short)f2bf(v0[j]);
        u[4 + j] = (short)f2bf(v1[j]);
      }
      *(short8*)&wlds[n * 256 + ((kc ^ (n & 7)) << 3)] = u;
    }
  }
  __syncthreads();  // the ONLY barrier

  float bv[8];
  {
    const float* bp = bias + kb * 256 + wn * 128 + ln;
#pragma unroll
    for (int ni = 0; ni < 8; ++ni) bv[ni] = bp[ni * 16];
  }

  floatx4 acc[8];
  float* op = out + ((size_t)mg * 1024 + wm * 16 + lk * 4) * INF + kb * 256 + wn * 128 + ln;

  // compute one half-tile (ks = h*4 .. h*4+3) from staged fp32 regs
#define COMPH(buf, h)                                                          \
  _Pragma("unroll") for (int q = 0; q < 4; ++q) {                              \
    short8 af;                                                                 \
    _Pragma("unroll") for (int j = 0; j < 4; ++j) {                            \
      af[j]     = (short)f2bf(sA[buf][q][0][j]);                               \
      af[4 + j] = (short)f2bf(sA[buf][q][1][j]);                               \
    }                                                                          \
    const int cc = ((h) * 4 + q) * 4 + lk;                                     \
    _Pragma("unroll") for (int ni = 0; ni < 8; ++ni) {                         \
      const int n = wn * 128 + ni * 16 + ln;                                   \
      const short8 bf = *(const short8*)&wlds[n * 256 + ((cc ^ (n & 7)) << 3)];\
      acc[ni] = __builtin_amdgcn_mfma_f32_16x16x32_bf16(af, bf, acc[ni], 0, 0, 0); \
    }                                                                          \
  }

  for (int t = 0; t < 16; ++t) {
#pragma unroll
    for (int ni = 0; ni < 8; ++ni)
#pragma unroll
      for (int e = 0; e < 4; ++e) acc[ni][e] = 0.0f;

    LOADH(1, t, 1)              // issue half-1 loads; compute below hides them
    COMPH(0, 0)
    if (t < 15) LOADH(0, t + 1, 0)  // issue next tile's half-0
    COMPH(1, 1)

    // epilogue: bias + store (frag: col = ln, row = lk*4 + j)
#pragma unroll
    for (int ni = 0; ni < 8; ++ni)
#pragma unroll
      for (int j = 0; j < 4; ++j)
        op[((size_t)t * 64 + j) * INF + ni * 16] = acc[ni][j] + bv[ni];
  }

#undef LOADH
#undef COMPH
}

extern "C" void kernel_launch(void* const* d_in, const int* in_sizes, int n_in,
                              void* d_out, int out_size, void* d_ws, size_t ws_size,
                              hipStream_t stream) {
  const float* x = (const float*)d_in[0];
  const float* W = (const float*)d_in[1];
  const float* b = (const float*)d_in[2];
  float* out = (float*)d_out;
  // 16 k-blocks x 16 m-groups = 256 WGs (1 per CU), 512 threads each
  hipLaunchKernelGGL(bd_gemm, dim3(256), dim3(512), 0, stream, x, W, b, out);
}

// Round 3
// 136.187 us; speedup vs baseline: 1.8104x; 1.8104x over previous
//
#include <hip/hip_runtime.h>

typedef short short8 __attribute__((ext_vector_type(8)));
typedef short short4v __attribute__((ext_vector_type(4)));
typedef float floatx4 __attribute__((ext_vector_type(4)));

#define INF 4096

// fp32 -> bf16 round-to-nearest-even
__device__ __forceinline__ ushort f2bf(float f) {
  unsigned u = __builtin_bit_cast(unsigned, f);
  u += 0x7fffu + ((u >> 16) & 1u);
  return (ushort)(u >> 16);
}

// Block-diagonal GEMM, v3: all global accesses wave-contiguous.
// Grid: 256 WGs = 16 k-blocks (low bits: 2 W-blocks per XCD, L2-resident)
//       x 16 m-groups of 1024 rows. 512 threads = 8 waves, 1 WG/CU.
// W_k: in REGISTERS. Wave w owns out-cols [w*32, w*32+32): 2 n-frags x 8 k-chunks
//      = 16 short8 frags (64 VGPR), loaded once, reused for all 16 m-tiles.
// x:   streamed through LDS. Tile = 64 rows x 256 k bf16 (32 KB), double-buffered.
//      Global load: one dwordx4/lane = one full row per wave instruction (1 KB
//      contiguous) -- fixes the round-1/2 segment-scatter that capped HBM at 2.8 TB/s.
//      Reg double-buffer g[2][8]; loads for t+1 issued BEFORE compute(t) so the
//      cvt's vmcnt wait never sits behind the tile-t stores.
// MFMA: swapped operands mfma(W_frag, x_frag) -> D[n][m]: lane holds 4 consecutive
//      out-cols -> bias+store as dwordx4.
__global__ __launch_bounds__(512, 1) void bd_gemm(
    const float* __restrict__ x, const float* __restrict__ W,
    const float* __restrict__ bias, float* __restrict__ out)
{
  __shared__ ushort xlds[2][64 * 256];  // [buf][row][k] bf16, 16B-chunk XOR swizzle

  const int bid  = blockIdx.x;
  const int kb   = bid & 15;
  const int mg   = bid >> 4;
  const int tid  = threadIdx.x;
  const int lane = tid & 63;
  const int w    = tid >> 6;   // wave 0..7 -> out-col slice
  const int ln   = lane & 15;
  const int lk   = lane >> 4;  // 0..3

  const float* xbase = x   + (size_t)(mg * 1024) * INF + kb * 256;
  float*       obase = out + (size_t)(mg * 1024) * INF + kb * 256 + w * 32;

  floatx4 g[2][8];  // reg staging: 8 rows/wave/tile, 16B/lane

  // one wave instruction = one contiguous 1KB row read
#define LOADX(set, t)                                                         \
  _Pragma("unroll") for (int i = 0; i < 8; ++i)                               \
    g[set][i] = *(const floatx4*)(xbase + (size_t)((t) * 64 + w * 8 + i) * INF + lane * 4);

  // cvt + swizzled LDS write; one wave instruction = one 512B row, conflict-free
#define WRITEX(set, buf)                                                      \
  _Pragma("unroll") for (int i = 0; i < 8; ++i) {                             \
    const int lr = w * 8 + i;                                                 \
    short4v u;                                                                \
    _Pragma("unroll") for (int j = 0; j < 4; ++j) u[j] = (short)f2bf(g[set][i][j]); \
    *(short4v*)((char*)&xlds[buf][0] +                                        \
        lr * 512 + ((((lane >> 1) ^ (lr & 7)) << 4) | ((lane & 1) << 3))) = u; \
  }

  // compute + store one 64-row tile from LDS buf
#define COMPUTE(buf, t)                                                       \
  {                                                                           \
    floatx4 acc[8];                                                           \
    _Pragma("unroll") for (int a = 0; a < 8; ++a)                             \
      _Pragma("unroll") for (int e = 0; e < 4; ++e) acc[a][e] = 0.0f;         \
    _Pragma("unroll") for (int kc = 0; kc < 8; ++kc) {                        \
      short8 xf[4];                                                           \
      _Pragma("unroll") for (int mi = 0; mi < 4; ++mi) {                      \
        const int lr = mi * 16 + ln;                                          \
        xf[mi] = *(const short8*)((const char*)&xlds[buf][0] +                \
                 lr * 512 + (((kc * 4 + lk) ^ (lr & 7)) << 4));               \
      }                                                                       \
      _Pragma("unroll") for (int mi = 0; mi < 4; ++mi)                        \
        _Pragma("unroll") for (int ni = 0; ni < 2; ++ni)                      \
          acc[mi * 2 + ni] = __builtin_amdgcn_mfma_f32_16x16x32_bf16(         \
              wf[ni][kc], xf[mi], acc[mi * 2 + ni], 0, 0, 0);                 \
    }                                                                         \
    _Pragma("unroll") for (int mi = 0; mi < 4; ++mi)                          \
      _Pragma("unroll") for (int ni = 0; ni < 2; ++ni) {                      \
        floatx4 r = acc[mi * 2 + ni];                                         \
        _Pragma("unroll") for (int j = 0; j < 4; ++j) r[j] += bv[ni][j];      \
        *(floatx4*)(obase + (size_t)((t) * 64 + mi * 16 + ln) * INF +         \
                    ni * 16 + lk * 4) = r;                                    \
      }                                                                       \
  }

  // ---- prologue: x tile-0 loads first (latency hidden by W-frag setup) ----
  LOADX(0, 0)

  // W frags: wave w cols [w*32, w*32+32): A-operand layout A[row=ln][k=lk*8+e]
  short8 wf[2][8];
  {
    const float* wp = W + (size_t)kb * 65536 + (w * 32 + ln) * 256 + lk * 8;
#pragma unroll
    for (int ni = 0; ni < 2; ++ni)
#pragma unroll
      for (int kc = 0; kc < 8; ++kc) {
        const float* s = wp + ni * 16 * 256 + kc * 32;
        floatx4 v0 = *(const floatx4*)s;
        floatx4 v1 = *(const floatx4*)(s + 4);
        short8 u;
#pragma unroll
        for (int j = 0; j < 4; ++j) {
          u[j]     = (short)f2bf(v0[j]);
          u[4 + j] = (short)f2bf(v1[j]);
        }
        wf[ni][kc] = u;
      }
  }
  floatx4 bv[2];
#pragma unroll
  for (int ni = 0; ni < 2; ++ni)
    bv[ni] = *(const floatx4*)(bias + kb * 256 + w * 32 + ni * 16 + lk * 4);

  WRITEX(0, 0)
  __syncthreads();

  // ---- main loop: 16 tiles of 64 rows, reg+LDS double-buffered ----
  for (int tt = 0; tt < 8; ++tt) {
    const int t0 = tt * 2, t1 = tt * 2 + 1;
    LOADX(1, t1)                 // issue next loads before compute: vmcnt wait
    COMPUTE(0, t0)               //   for them never sits behind these stores
    WRITEX(1, 1)
    __syncthreads();
    if (t1 < 15) LOADX(0, t1 + 1)
    COMPUTE(1, t1)
    if (t1 < 15) {
      WRITEX(0, 0)
      __syncthreads();
    }
  }

#undef LOADX
#undef WRITEX
#undef COMPUTE
}

extern "C" void kernel_launch(void* const* d_in, const int* in_sizes, int n_in,
                              void* d_out, int out_size, void* d_ws, size_t ws_size,
                              hipStream_t stream) {
  const float* x = (const float*)d_in[0];
  const float* W = (const float*)d_in[1];
  const float* b = (const float*)d_in[2];
  float* out = (float*)d_out;
  // 16 k-blocks x 16 m-groups = 256 WGs (1/CU), 512 threads (8 waves)
  hipLaunchKernelGGL(bd_gemm, dim3(256), dim3(512), 0, stream, x, W, b, out);
}